// Round 1
// baseline (259.750 us; speedup 1.0000x reference)
//
#include <hip/hip_runtime.h>
#include <hip/hip_bf16.h>
#include <cstdint>

// Problem constants (from reference): B=32, C=256, P=32, H=56, W=56
#define B_  32
#define C_  256
#define P_  32
#define HW_ 3136          // 56*56
#define KT  32            // K-tile (hw) per staging round
#define NTILES (HW_ / KT) // 98
#define KSPLIT 32         // K-split factor for parallelism

// -------------------------------------------------------------------------
// Kernel 1: att[b,hw] = sigmoid( sum_p part[b,p,hw]*conv_w[p] + conv_b )
// float4 over hw; p-loop loads are coalesced (fixed p => consecutive hw).
// -------------------------------------------------------------------------
__global__ __launch_bounds__(256) void att_kernel(
    const float* __restrict__ part,     // [B,P,HW]
    const float* __restrict__ conv_w,   // [P]
    const float* __restrict__ conv_b,   // [1]
    float* __restrict__ att)            // [B,HW]
{
    const int HW4 = HW_ / 4;                 // 784
    int i4 = blockIdx.x * blockDim.x + threadIdx.x;   // over B*HW/4 = 25088
    if (i4 >= B_ * HW4) return;
    int b  = i4 / HW4;
    int hw = (i4 - b * HW4) * 4;

    const float* pb = part + (size_t)b * P_ * HW_ + hw;
    float bias = conv_b[0];
    float4 z = make_float4(bias, bias, bias, bias);
#pragma unroll
    for (int p = 0; p < P_; ++p) {
        float w = conv_w[p];                 // uniform -> scalar load
        float4 v = *(const float4*)(pb + (size_t)p * HW_);
        z.x += v.x * w; z.y += v.y * w; z.z += v.z * w; z.w += v.w * w;
    }
    float4 s;
    s.x = 1.0f / (1.0f + __expf(-z.x));
    s.y = 1.0f / (1.0f + __expf(-z.y));
    s.z = 1.0f / (1.0f + __expf(-z.z));
    s.w = 1.0f / (1.0f + __expf(-z.w));
    *(float4*)(att + (size_t)b * HW_ + hw) = s;
}

// -------------------------------------------------------------------------
// Kernel 2: batched GEMM  feats[b,p,c] = sum_hw part[b,p,hw] * x[b,c,hw]*att[b,hw]
// Block tile: M=32 (all P) x N=256 (all C), K-tile=32, K split KSPLIT ways.
// 256 threads; thread tile 4(p) x 8(c). fp32 atomicAdd epilogue.
// LDS stride 33 => compute-loop reads conflict-free (banks (cg+k)%32, As broadcast).
// -------------------------------------------------------------------------
__global__ __launch_bounds__(256) void gemm_kernel(
    const float* __restrict__ x,        // [B,C,HW]
    const float* __restrict__ part,     // [B,P,HW]
    const float* __restrict__ att,      // [B,HW]
    float* __restrict__ out)            // [B, P*C]
{
    __shared__ float As[P_][KT + 1];    // 32 x 33  (part tile)
    __shared__ float Bs[C_][KT + 1];    // 256 x 33 (x*att tile)   total 38,016 B

    const int b  = blockIdx.y;
    const int kc = blockIdx.x;
    const int t0 = (NTILES * kc) / KSPLIT;
    const int t1 = (NTILES * (kc + 1)) / KSPLIT;

    const int tid = threadIdx.x;
    const int pg  = tid >> 5;   // 0..7 : p-group (4 p's each)
    const int cg  = tid & 31;   // 0..31: c base within 32-lane group

    const float* xb = x    + (size_t)b * C_ * HW_;
    const float* pb = part + (size_t)b * P_ * HW_;
    const float* ab = att  + (size_t)b * HW_;

    float acc[4][8];
#pragma unroll
    for (int i = 0; i < 4; ++i)
#pragma unroll
        for (int j = 0; j < 8; ++j) acc[i][j] = 0.0f;

    for (int t = t0; t < t1; ++t) {
        const int kbase = t * KT;

        // ---- stage As: 32x32 floats = 256 float4, one per thread ----
        {
            int p  = tid >> 3;              // 0..31
            int k4 = (tid & 7) << 2;        // 0,4,...,28
            float4 v = *(const float4*)(pb + (size_t)p * HW_ + kbase + k4);
            As[p][k4 + 0] = v.x; As[p][k4 + 1] = v.y;
            As[p][k4 + 2] = v.z; As[p][k4 + 3] = v.w;
        }
        // ---- stage Bs: 256x32 floats = 2048 float4, 8 per thread; fold att ----
#pragma unroll
        for (int l = 0; l < 8; ++l) {
            int s  = (l << 8) + tid;        // 0..2047
            int c  = s >> 3;
            int k4 = (s & 7) << 2;
            float4 v  = *(const float4*)(xb + (size_t)c * HW_ + kbase + k4);
            float4 a4 = *(const float4*)(ab + kbase + k4);   // L1-hot, 256x reuse
            Bs[c][k4 + 0] = v.x * a4.x; Bs[c][k4 + 1] = v.y * a4.y;
            Bs[c][k4 + 2] = v.z * a4.z; Bs[c][k4 + 3] = v.w * a4.w;
        }
        __syncthreads();

        // ---- compute: 32 k-iters, 12 LDS reads + 32 FMA per iter per thread ----
#pragma unroll
        for (int k = 0; k < KT; ++k) {
            float a0 = As[pg * 4 + 0][k];
            float a1 = As[pg * 4 + 1][k];
            float a2 = As[pg * 4 + 2][k];
            float a3 = As[pg * 4 + 3][k];
#pragma unroll
            for (int j = 0; j < 8; ++j) {
                float bv = Bs[cg + (j << 5)][k];
                acc[0][j] += a0 * bv;
                acc[1][j] += a1 * bv;
                acc[2][j] += a2 * bv;
                acc[3][j] += a3 * bv;
            }
        }
        __syncthreads();
    }

    // ---- epilogue: atomic accumulate K-split partials ----
    float* ob = out + (size_t)b * P_ * C_;
#pragma unroll
    for (int i = 0; i < 4; ++i) {
        int p = pg * 4 + i;
#pragma unroll
        for (int j = 0; j < 8; ++j) {
            atomicAdd(&ob[p * C_ + cg + (j << 5)], acc[i][j]);
        }
    }
}

extern "C" void kernel_launch(void* const* d_in, const int* in_sizes, int n_in,
                              void* d_out, int out_size, void* d_ws, size_t ws_size,
                              hipStream_t stream) {
    const float* x      = (const float*)d_in[0];   // [B,C,H,W]
    const float* part   = (const float*)d_in[1];   // [B,P,H,W]
    const float* conv_w = (const float*)d_in[2];   // [P]
    const float* conv_b = (const float*)d_in[3];   // [1]
    float* out = (float*)d_out;                    // [B, P*C] = 262144 floats
    float* att = (float*)d_ws;                     // [B,HW] = 401,408 B scratch

    // zero d_out (harness poisons it to 0xAA before every timed launch)
    hipMemsetAsync(d_out, 0, (size_t)out_size * sizeof(float), stream);

    // att pass: B*HW/4 = 25088 threads
    att_kernel<<<dim3((B_ * (HW_ / 4) + 255) / 256), dim3(256), 0, stream>>>(
        part, conv_w, conv_b, att);

    // batched GEMM with K-split
    gemm_kernel<<<dim3(KSPLIT, B_), dim3(256), 0, stream>>>(x, part, att, out);
}

// Round 2
// 175.919 us; speedup vs baseline: 1.4765x; 1.4765x over previous
//
#include <hip/hip_runtime.h>
#include <cstdint>

// Problem constants: B=32, C=256, P=32, H=W=56
#define B_  32
#define C_  256
#define P_  32
#define HW_ 3136
#define KT  32            // K-tile per staging round (== MFMA K depth)
#define NT  98            // HW_/KT
#define KSPLIT_MAX 16

typedef __attribute__((ext_vector_type(8))) short   short8;   // 8 x bf16 (MFMA A/B frag)
typedef __attribute__((ext_vector_type(4))) float   floatx4;  // MFMA C/D frag

__device__ __forceinline__ unsigned short f2bf(float f) {
    // round-to-nearest-even f32 -> bf16
    union { float f; unsigned u; } v; v.f = f;
    unsigned r = v.u + 0x7fffu + ((v.u >> 16) & 1u);
    return (unsigned short)(r >> 16);
}

// ---------------------------------------------------------------------------
// Stage 1: fused att + batched bf16-MFMA GEMM, K-split partials (plain stores).
// Block: 256 threads (4 waves). Tile M=32 (all p) x N=256 (all c) x KT=32.
// Per round: load part(1 f4/thr) + x(8 f4/thr) -> stage Apf(f32)+Abf(bf16) ->
// att from Apf -> scale x, stage Bbf(bf16) -> 16x16x32 bf16 MFMA.
// att is computed per-thread for its own k-quad (no extra barrier): 3 barriers/round.
// ---------------------------------------------------------------------------
__global__ __launch_bounds__(256) void gemm_fused(
    const float* __restrict__ x,        // [B,C,HW]
    const float* __restrict__ part,     // [B,P,HW]
    const float* __restrict__ conv_w,   // [P]
    const float* __restrict__ conv_b,   // [1]
    float* __restrict__ partial,        // [ksplit, B, P, C]
    int ksplit)
{
    __shared__ float          Apf[P_][36];   // part tile f32 (for att)     4,608 B
    __shared__ unsigned short Abf[P_][40];   // part tile bf16 (A operand)  2,560 B
    __shared__ unsigned short Bbf[C_][40];   // (x*att) tile bf16 (B op)   20,480 B

    const int b  = blockIdx.y;
    const int kc = blockIdx.x;
    const int t0 = kc * NT / ksplit;
    const int t1 = (kc + 1) * NT / ksplit;

    const int tid  = threadIdx.x;
    const int lane = tid & 63;
    const int wv   = tid >> 6;        // wave 0..3 -> c-range wv*64
    const int qd   = lane >> 4;       // quad 0..3
    const int r15  = lane & 15;

    // staging mapping: thread handles row sp, k-quad k4
    const int sp = tid >> 3;          // 0..31
    const int k4 = (tid & 7) << 2;    // 0,4,...,28

    const float* xb = x    + (size_t)b * C_ * HW_;
    const float* pb = part + (size_t)b * P_ * HW_;
    const float  bias = conv_b[0];

    floatx4 acc[2][4];
#pragma unroll
    for (int mt = 0; mt < 2; ++mt)
#pragma unroll
        for (int nt = 0; nt < 4; ++nt) acc[mt][nt] = (floatx4)0.0f;

    for (int t = t0; t < t1; ++t) {
        const int kb = t * KT;

        // ---- issue all global loads for this round up front ----
        float4 pv = *(const float4*)(pb + (size_t)sp * HW_ + kb + k4);
        float4 xv[8];
#pragma unroll
        for (int j = 0; j < 8; ++j) {
            int c = (j << 5) + sp;
            xv[j] = *(const float4*)(xb + (size_t)c * HW_ + kb + k4);
        }

        // ---- stage part: f32 (for att) + bf16 (A operand) ----
        *(float4*)&Apf[sp][k4] = pv;
        {
            ushort4 a4;
            a4.x = f2bf(pv.x); a4.y = f2bf(pv.y);
            a4.z = f2bf(pv.z); a4.w = f2bf(pv.w);
            *(ushort4*)&Abf[sp][k4] = a4;
        }
        __syncthreads();   // Apf/Abf ready

        // ---- att for this thread's k-quad: z[i] = bias + sum_p Apf[p][k4+i]*w[p] ----
        float z0 = bias, z1 = bias, z2 = bias, z3 = bias;
#pragma unroll
        for (int p = 0; p < P_; ++p) {
            float4 a = *(const float4*)&Apf[p][k4];   // b128, 8 distinct addrs -> broadcast
            float  wp = conv_w[p];                    // uniform -> scalar load
            z0 += a.x * wp; z1 += a.y * wp; z2 += a.z * wp; z3 += a.w * wp;
        }
        float at0 = 1.0f / (1.0f + __expf(-z0));
        float at1 = 1.0f / (1.0f + __expf(-z1));
        float at2 = 1.0f / (1.0f + __expf(-z2));
        float at3 = 1.0f / (1.0f + __expf(-z3));

        // ---- scale x by att, convert, stage B operand ----
#pragma unroll
        for (int j = 0; j < 8; ++j) {
            int c = (j << 5) + sp;
            ushort4 b4;
            b4.x = f2bf(xv[j].x * at0); b4.y = f2bf(xv[j].y * at1);
            b4.z = f2bf(xv[j].z * at2); b4.w = f2bf(xv[j].w * at3);
            *(ushort4*)&Bbf[c][k4] = b4;
        }
        __syncthreads();   // Bbf ready

        // ---- MFMA: wave covers c in [wv*64, wv*64+64), all 32 p ----
        short8 af[2], bf[4];
#pragma unroll
        for (int mt = 0; mt < 2; ++mt)
            af[mt] = *(const short8*)&Abf[mt * 16 + r15][qd * 8];
#pragma unroll
        for (int nt = 0; nt < 4; ++nt)
            bf[nt] = *(const short8*)&Bbf[wv * 64 + nt * 16 + r15][qd * 8];
#pragma unroll
        for (int mt = 0; mt < 2; ++mt)
#pragma unroll
            for (int nt = 0; nt < 4; ++nt)
                acc[mt][nt] = __builtin_amdgcn_mfma_f32_16x16x32_bf16(
                    af[mt], bf[nt], acc[mt][nt], 0, 0, 0);
        __syncthreads();   // LDS free for next round's staging
    }

    // ---- epilogue: plain stores of K-split partials (NO atomics) ----
    // D layout: row(m=p) = qd*4 + reg, col(n=c) = r15
    float* ob = partial + ((size_t)kc * B_ + b) * (P_ * C_);
#pragma unroll
    for (int mt = 0; mt < 2; ++mt) {
#pragma unroll
        for (int nt = 0; nt < 4; ++nt) {
#pragma unroll
            for (int rg = 0; rg < 4; ++rg) {
                int p = mt * 16 + qd * 4 + rg;
                int c = wv * 64 + nt * 16 + r15;
                ob[p * C_ + c] = acc[mt][nt][rg];
            }
        }
    }
}

// ---------------------------------------------------------------------------
// Stage 2: out[i] = sum_kc partial[kc][i].  float4 over 262144 floats.
// ---------------------------------------------------------------------------
__global__ __launch_bounds__(256) void reduce_k(
    const float* __restrict__ partial, float* __restrict__ out, int ksplit)
{
    int i = blockIdx.x * 256 + threadIdx.x;       // over 65536 float4s
    const float4* p4 = (const float4*)partial;
    float4 s = p4[i];
    for (int kc = 1; kc < ksplit; ++kc) {
        float4 v = p4[(size_t)kc * (B_ * P_ * C_ / 4) + i];
        s.x += v.x; s.y += v.y; s.z += v.z; s.w += v.w;
    }
    ((float4*)out)[i] = s;
}

extern "C" void kernel_launch(void* const* d_in, const int* in_sizes, int n_in,
                              void* d_out, int out_size, void* d_ws, size_t ws_size,
                              hipStream_t stream) {
    const float* x      = (const float*)d_in[0];
    const float* part   = (const float*)d_in[1];
    const float* conv_w = (const float*)d_in[2];
    const float* conv_b = (const float*)d_in[3];

    // ksplit clamped to available workspace (deterministic per ws_size -> graph-safe)
    size_t slab = (size_t)B_ * P_ * C_ * 4;
    int ksplit = (int)(ws_size / slab);
    if (ksplit > KSPLIT_MAX) ksplit = KSPLIT_MAX;
    if (ksplit < 1) ksplit = 1;

    float* partial = (ksplit > 1) ? (float*)d_ws : (float*)d_out;

    gemm_fused<<<dim3(ksplit, B_), dim3(256), 0, stream>>>(
        x, part, conv_w, conv_b, partial, ksplit);

    if (ksplit > 1) {
        reduce_k<<<dim3((B_ * P_ * C_ / 4) / 256), dim3(256), 0, stream>>>(
            (const float*)d_ws, (float*)d_out, ksplit);
    }
}